// Round 1
// baseline (1778.627 us; speedup 1.0000x reference)
//
#include <hip/hip_runtime.h>
#include <math.h>

#define NN 256
#define BB 1024
#define NMAT 1025   // 1024 batch matrices + 1 for L0

// Static device storage (harness ws not used; everything rewritten every launch)
__device__ float g_T[4][NN*NN];      // T[c][j*256+i] = Ws(i,j)*E(i,j,a,b)/(V[i][a]V[j][b]), c=2a+b
__device__ float g_Ws[NN*NN];        // Ws[j*256+i] (symmetric)
__device__ float g_V[NN][2];
__device__ float g_ld[NMAT];
__device__ float g_slab[NMAT][NN*NN]; // col-major A[col*256+row]

__device__ __forceinline__ float sigmf(float v) { return 1.0f / (1.0f + expf(-v)); }

__global__ void k_prep_v(const float* __restrict__ Vc) {
  int i = threadIdx.x;
  float a = sigmf(Vc[2*i]);
  float b = sigmf(Vc[2*i+1]);
  float s = a + b;
  g_V[i][0] = a / s;
  g_V[i][1] = b / s;
}

__global__ void k_prep_T(const float* __restrict__ W, const float* __restrict__ lam) {
  int j = blockIdx.x;
  int i = threadIdx.x;
  float vi0 = g_V[i][0], vi1 = g_V[i][1];
  float vj0 = g_V[j][0], vj1 = g_V[j][1];
  float ws;
  if (i > j)      ws = sigmf(W[i*NN + j]);
  else if (i < j) ws = sigmf(W[j*NN + i]);
  else            ws = 0.0f;
  g_Ws[j*NN + i] = ws;
  float s = sigmf(lam[i*NN + j]);
  float pi = vi0, pj = vj0;
  float lower = fmaxf(1e-7f, pi + pj - 1.0f);
  float upper = fminf(pi, pj);
  float P00 = lower + s * (upper - lower);
  float P01 = pi - P00;
  float P10 = pj - P00;
  float P11 = 1.0f - pi - pj + P00;
  if (i == j) { P00 = P01 = P10 = P11 = 0.0f; }
  P00 = fminf(fmaxf(P00, 0.0f), 1.0f);
  P01 = fminf(fmaxf(P01, 0.0f), 1.0f);
  P10 = fminf(fmaxf(P10, 0.0f), 1.0f);
  P11 = fminf(fmaxf(P11, 0.0f), 1.0f);
  int o = j*NN + i;
  g_T[0][o] = ws * P00 / (vi0 * vj0);
  g_T[1][o] = ws * P01 / (vi0 * vj1);
  g_T[2][o] = ws * P10 / (vi1 * vj0);
  g_T[3][o] = ws * P11 / (vi1 * vj1);
}

// One workgroup per matrix. Thread t owns matrix row t. Col-major slab.
// Blocked no-pivot LU, NB=64, 4 phases. Row-diagonally-dominant => stable.
__global__ __launch_bounds__(256) void k_lu(const int* __restrict__ x) {
  __shared__ float Utop[192][68];   // U row-panel, [col][k], padded rows (16B aligned)
  __shared__ float Lt[64][68];      // panel-top 64x64 multipliers
  __shared__ float urow[2][68];     // double-buffered pivot row
  __shared__ float pivbuf[NN];
  __shared__ int   xs[NN];
  __shared__ float red[4];

  const int t = threadIdx.x;
  const int m = blockIdx.x;
  float* __restrict__ A = g_slab[m];

  if (m < BB) xs[t] = x[m*NN + t];
  __syncthreads();

  float preg[64];   // this thread's row segment of the current panel

  // ---- build: row t of shifted/padded matrix. Panel-0 cols (0..63) built
  //      directly into registers; cols 64..255 to global slab. ----
  {
    float rowsum = 0.0f;
    if (m < BB) {
      const int a = (t < NN-1) ? xs[t+1] : 0;
      const float* TA = &g_T[2*a][0] + (t + 1);
      #pragma unroll
      for (int jj = 0; jj < 64; ++jj) {       // cols 0..63 -> preg
        int bcl = xs[jj+1];
        float w = 0.0f;
        if (t < 255) w = TA[bcl*(NN*NN) + (jj+1)*NN];
        rowsum += w;
        preg[jj] = -w;
      }
      #pragma unroll 4
      for (int jj = 64; jj < 255; ++jj) {     // cols 64..254 -> slab
        int bcl = xs[jj+1];
        float w = 0.0f;
        if (t < 255) w = TA[bcl*(NN*NN) + (jj+1)*NN];
        rowsum += w;
        A[jj*NN + t] = -w;
      }
      if (t < 255) rowsum += TA[xs[0]*(NN*NN)];   // j=0 column term
    } else {
      // L0 matrix: w = Ws(t+1, jj+1)
      #pragma unroll
      for (int jj = 0; jj < 64; ++jj) {
        float w = 0.0f;
        if (t < 255) w = g_Ws[(jj+1)*NN + (t+1)];
        rowsum += w;
        preg[jj] = -w;
      }
      #pragma unroll 4
      for (int jj = 64; jj < 255; ++jj) {
        float w = 0.0f;
        if (t < 255) w = g_Ws[(jj+1)*NN + (t+1)];
        rowsum += w;
        A[jj*NN + t] = -w;
      }
      if (t < 255) rowsum += g_Ws[t + 1];
    }
    A[255*NN + t] = (t == 255) ? 1.0f : 0.0f;     // pad column
    if (t >= 64 && t < 255) A[t*NN + t] = rowsum; // diagonal (global part)
    if (t < 64) {                                  // diagonal inside panel-0 regs
      #pragma unroll
      for (int c = 0; c < 64; ++c) if (t == c) preg[c] = rowsum;
    }
  }

  for (int s = 0; s < 4; ++s) {
    const int k0 = s * 64;
    const int k1 = k0 + 64;
    const int wcols = NN - k1;   // 192,128,64,0

    if (s > 0 && t >= k0) {      // phase 0 panel already in regs from build
      #pragma unroll
      for (int c = 0; c < 64; ++c) preg[c] = A[(k0+c)*NN + t];
    }
    __syncthreads();

    // ---- panel factorization (64 pivots, fully unrolled, regs + urow bcast) ----
    #pragma unroll
    for (int kk = 0; kk < 64; ++kk) {
      float* ur = urow[kk & 1];
      if (t == k0 + kk) {
        #pragma unroll
        for (int q = (kk >> 2); q < 16; ++q) {
          float4 v; v.x = preg[4*q]; v.y = preg[4*q+1]; v.z = preg[4*q+2]; v.w = preg[4*q+3];
          *(float4*)&ur[4*q] = v;
        }
        pivbuf[k0 + kk] = preg[kk];
      }
      __syncthreads();
      if (t > k0 + kk) {
        float mlt = preg[kk] * __builtin_amdgcn_rcpf(ur[kk]);
        preg[kk] = mlt;
        #pragma unroll
        for (int j = kk + 1; j < ((kk + 4) & ~3) && j < 64; ++j)
          preg[j] -= mlt * ur[j];
        #pragma unroll
        for (int q = ((kk + 4) >> 2); q < 16; ++q) {
          float4 u4 = *(const float4*)&ur[4*q];
          preg[4*q+0] -= mlt * u4.x;
          preg[4*q+1] -= mlt * u4.y;
          preg[4*q+2] -= mlt * u4.z;
          preg[4*q+3] -= mlt * u4.w;
        }
      }
    }

    if (wcols > 0) {
      // dump panel-top block (multipliers) for the tri-solve
      if (t >= k0 && t < k1) {
        const int r = t - k0;
        #pragma unroll
        for (int q = 0; q < 16; ++q) {
          float4 v; v.x = preg[4*q]; v.y = preg[4*q+1]; v.z = preg[4*q+2]; v.w = preg[4*q+3];
          *(float4*)&Lt[r][4*q] = v;
        }
      }
      // cooperative load of A_top (rows k0..k0+63, cols k1..255) into Utop[col][k]
      for (int idx = t; idx < (wcols << 6); idx += NN) {
        int r = idx & 63, cc = idx >> 6;
        Utop[cc][r] = A[(k1 + cc)*NN + (k0 + r)];
      }
      __syncthreads();

      // ---- tri-solve: U = Ltop^{-1} * Atop, one column per thread, in regs ----
      if (t < wcols) {
        float u[64];
        #pragma unroll
        for (int rr = 0; rr < 16; ++rr) {
          float4 v = *(const float4*)&Utop[t][4*rr];
          u[4*rr] = v.x; u[4*rr+1] = v.y; u[4*rr+2] = v.z; u[4*rr+3] = v.w;
        }
        #pragma unroll
        for (int q = 0; q < 16; ++q) {
          u[4*q+1] -= Lt[4*q+1][4*q+0]*u[4*q+0];
          u[4*q+2] -= Lt[4*q+2][4*q+0]*u[4*q+0];
          u[4*q+2] -= Lt[4*q+2][4*q+1]*u[4*q+1];
          u[4*q+3] -= Lt[4*q+3][4*q+0]*u[4*q+0];
          u[4*q+3] -= Lt[4*q+3][4*q+1]*u[4*q+1];
          u[4*q+3] -= Lt[4*q+3][4*q+2]*u[4*q+2];
          #pragma unroll
          for (int r = 4*q + 4; r < 64; ++r) {
            float4 l4 = *(const float4*)&Lt[r][4*q];
            float acc = u[r];
            acc -= l4.x * u[4*q+0];
            acc -= l4.y * u[4*q+1];
            acc -= l4.z * u[4*q+2];
            acc -= l4.w * u[4*q+3];
            u[r] = acc;
          }
        }
        #pragma unroll
        for (int rr = 0; rr < 16; ++rr) {
          float4 v; v.x = u[4*rr]; v.y = u[4*rr+1]; v.z = u[4*rr+2]; v.w = u[4*rr+3];
          *(float4*)&Utop[t][4*rr] = v;
        }
      }
      __syncthreads();

      // ---- trailing update: A[i][j] -= L[i][:64] . U[:64][j] ----
      if (t >= k1) {
        for (int j = 0; j < wcols; j += 2) {
          float c0 = A[(k1 + j    )*NN + t];
          float c1 = A[(k1 + j + 1)*NN + t];
          const float4* U0 = (const float4*)&Utop[j][0];
          const float4* U1 = (const float4*)&Utop[j + 1][0];
          #pragma unroll
          for (int q = 0; q < 16; ++q) {
            float4 a4 = U0[q], b4 = U1[q];
            c0 -= preg[4*q+0]*a4.x;  c1 -= preg[4*q+0]*b4.x;
            c0 -= preg[4*q+1]*a4.y;  c1 -= preg[4*q+1]*b4.y;
            c0 -= preg[4*q+2]*a4.z;  c1 -= preg[4*q+2]*b4.z;
            c0 -= preg[4*q+3]*a4.w;  c1 -= preg[4*q+3]*b4.w;
          }
          A[(k1 + j    )*NN + t] = c0;
          A[(k1 + j + 1)*NN + t] = c1;
        }
      }
      __syncthreads();
    }
  }

  __syncthreads();
  float lg = logf(fabsf(pivbuf[t]));
  #pragma unroll
  for (int off = 32; off > 0; off >>= 1) lg += __shfl_down(lg, off, 64);
  if ((t & 63) == 0) red[t >> 6] = lg;
  __syncthreads();
  if (t == 0) g_ld[m] = red[0] + red[1] + red[2] + red[3];
}

__global__ void k_final(const int* __restrict__ x, float* __restrict__ out) {
  __shared__ float red[4];
  int b = blockIdx.x, t = threadIdx.x;
  int xv = x[b*NN + t];
  float lg = logf(g_V[t][xv]);
  #pragma unroll
  for (int off = 32; off > 0; off >>= 1) lg += __shfl_down(lg, off, 64);
  if ((t & 63) == 0) red[t >> 6] = lg;
  __syncthreads();
  if (t == 0) out[b] = (red[0] + red[1] + red[2] + red[3]) + g_ld[b] - g_ld[BB];
}

extern "C" void kernel_launch(void* const* d_in, const int* in_sizes, int n_in,
                              void* d_out, int out_size, void* d_ws, size_t ws_size,
                              hipStream_t stream) {
  const float* W   = (const float*)d_in[0];
  const float* lam = (const float*)d_in[1];
  const float* Vc  = (const float*)d_in[2];
  const int*   x   = (const int*)d_in[3];
  float* out = (float*)d_out;

  k_prep_v<<<dim3(1),    dim3(NN), 0, stream>>>(Vc);
  k_prep_T<<<dim3(NN),   dim3(NN), 0, stream>>>(W, lam);
  k_lu    <<<dim3(NMAT), dim3(NN), 0, stream>>>(x);
  k_final <<<dim3(BB),   dim3(NN), 0, stream>>>(x, out);
}